// Round 1
// baseline (1310.490 us; speedup 1.0000x reference)
//
#include <hip/hip_runtime.h>
#include <math.h>

#define B_ 2
#define S_ 2048
#define D_ 1024
#define H_ 16
#define HD 64
#define M_ (B_ * S_)     // 4096 rows
#define N_QKV (3 * D_)   // 3072

// ---------------------------------------------------------------------------
// C[M,N] = A[M,K] @ B[K,N] + bias[N]
// 128x128 block tile, BK=8, 256 threads, 8x8 micro-tile per thread.
// M,N % 128 == 0, K % 8 == 0 for all call sites (no edge handling).
// ---------------------------------------------------------------------------
__global__ __launch_bounds__(256) void sgemm_bias(
    const float* __restrict__ A, const float* __restrict__ Bm,
    const float* __restrict__ bias, float* __restrict__ C,
    int M, int N, int K)
{
    __shared__ float As[8][128];   // A tile, transposed: As[k][m]
    __shared__ float Bs[8][128];   // B tile: Bs[k][n]

    const int t  = threadIdx.x;
    const int m0 = blockIdx.y * 128;
    const int n0 = blockIdx.x * 128;

    // global->LDS load mapping
    const int arow = t >> 1;           // 0..127
    const int akq  = (t & 1) * 4;      // 0 or 4
    const int brow = t >> 5;           // 0..7
    const int bcol = (t & 31) * 4;     // 0..124

    const float* Ap = A  + (size_t)(m0 + arow) * K + akq;
    const float* Bp = Bm + (size_t)brow * N + n0 + bcol;

    const int tx = t & 15;             // 0..15 -> N
    const int ty = t >> 4;             // 0..15 -> M

    float acc[8][8];
#pragma unroll
    for (int i = 0; i < 8; i++)
#pragma unroll
        for (int j = 0; j < 8; j++) acc[i][j] = 0.f;

    for (int k0 = 0; k0 < K; k0 += 8) {
        float4 av = *(const float4*)(Ap + k0);
        float4 bv = *(const float4*)(Bp + (size_t)k0 * N);
        As[akq + 0][arow] = av.x;
        As[akq + 1][arow] = av.y;
        As[akq + 2][arow] = av.z;
        As[akq + 3][arow] = av.w;
        *(float4*)&Bs[brow][bcol] = bv;
        __syncthreads();

#pragma unroll
        for (int kk = 0; kk < 8; kk++) {
            float4 a0 = *(const float4*)&As[kk][ty * 4];
            float4 a1 = *(const float4*)&As[kk][64 + ty * 4];
            float4 b0 = *(const float4*)&Bs[kk][tx * 4];
            float4 b1 = *(const float4*)&Bs[kk][64 + tx * 4];
            float ar[8] = {a0.x, a0.y, a0.z, a0.w, a1.x, a1.y, a1.z, a1.w};
            float br[8] = {b0.x, b0.y, b0.z, b0.w, b1.x, b1.y, b1.z, b1.w};
#pragma unroll
            for (int i = 0; i < 8; i++)
#pragma unroll
                for (int j = 0; j < 8; j++)
                    acc[i][j] = fmaf(ar[i], br[j], acc[i][j]);
        }
        __syncthreads();
    }

    // epilogue: add bias, store
#pragma unroll
    for (int i = 0; i < 8; i++) {
        const int r = (i < 4) ? (ty * 4 + i) : (64 + ty * 4 + (i - 4));
        float* Crow = C + (size_t)(m0 + r) * N + n0;
#pragma unroll
        for (int jh = 0; jh < 2; jh++) {
            const int c = jh * 64 + tx * 4;
            float4 o;
            o.x = acc[i][jh * 4 + 0] + bias[n0 + c + 0];
            o.y = acc[i][jh * 4 + 1] + bias[n0 + c + 1];
            o.z = acc[i][jh * 4 + 2] + bias[n0 + c + 2];
            o.w = acc[i][jh * 4 + 3] + bias[n0 + c + 3];
            *(float4*)(Crow + c) = o;
        }
    }
}

// ---------------------------------------------------------------------------
// Causal flash attention, fp32.
// qkv layout: [B, S, 3*D] with q at col h*64+d, k at +D, v at +2D.
// Block = 256 threads handles one (b, h, 32-row Q tile).
// Thread t: row qi = t>>3 for both phases; S-phase cols kj = (t&7)*4..+3;
//           P-phase output cols oc = (t&7)*8..+7.
// Online softmax state shared across the 8 lanes of a row via __shfl_xor.
// ---------------------------------------------------------------------------
#define TQ 32
#define TK 32

__global__ __launch_bounds__(256) void flash_attn(
    const float* __restrict__ qkv, float* __restrict__ out)
{
    __shared__ float Qs[TQ][HD + 4];   // stride 68: float4-aligned, <=2-way conflicts
    __shared__ float Ks[TK][HD + 1];   // stride 65: scalar access, conflict-free reads
    __shared__ float Vs[TK][HD + 4];   // stride 68
    __shared__ float Ps[TQ][TK + 1];   // stride 33

    const int t  = threadIdx.x;
    const int qt = blockIdx.x;
    const int bh = blockIdx.y;
    const int b  = bh >> 4;
    const int h  = bh & 15;
    const int q0 = qt * TQ;

    const int lrow = t >> 3;           // 0..31 (tile row for loads)
    const int ld   = (t & 7) * 8;      // 0..56 (col group for loads)

    // load Q tile
    {
        const float* src = qkv + ((size_t)(b * S_ + q0 + lrow)) * N_QKV + h * HD + ld;
        float4 v0 = *(const float4*)src;
        float4 v1 = *(const float4*)(src + 4);
        *(float4*)&Qs[lrow][ld]     = v0;
        *(float4*)&Qs[lrow][ld + 4] = v1;
    }

    const int qi   = t >> 3;
    const int kg   = t & 7;
    const int oc   = (t & 7) * 8;
    const int qabs = q0 + qi;
    const float scale = 0.125f;   // 1/sqrt(64)

    float m_i = -INFINITY, l_i = 0.f;
    float o[8];
#pragma unroll
    for (int i = 0; i < 8; i++) o[i] = 0.f;

    for (int k0 = 0; k0 < q0 + TQ; k0 += TK) {
        __syncthreads();   // previous iteration's P-phase done before K/V overwrite
        {
            const float* ksrc = qkv + ((size_t)(b * S_ + k0 + lrow)) * N_QKV + D_ + h * HD + ld;
            float4 kv0 = *(const float4*)ksrc;
            float4 kv1 = *(const float4*)(ksrc + 4);
            const float* vsrc = ksrc + D_;
            float4 vv0 = *(const float4*)vsrc;
            float4 vv1 = *(const float4*)(vsrc + 4);
            Ks[lrow][ld + 0] = kv0.x; Ks[lrow][ld + 1] = kv0.y;
            Ks[lrow][ld + 2] = kv0.z; Ks[lrow][ld + 3] = kv0.w;
            Ks[lrow][ld + 4] = kv1.x; Ks[lrow][ld + 5] = kv1.y;
            Ks[lrow][ld + 6] = kv1.z; Ks[lrow][ld + 7] = kv1.w;
            *(float4*)&Vs[lrow][ld]     = vv0;
            *(float4*)&Vs[lrow][ld + 4] = vv1;
        }
        __syncthreads();

        // ---- S = Q K^T for this tile: thread computes row qi, cols kg*4..+3
        float s0 = 0.f, s1 = 0.f, s2 = 0.f, s3 = 0.f;
#pragma unroll 8
        for (int d = 0; d < HD; d++) {
            float qv = Qs[qi][d];
            s0 = fmaf(qv, Ks[kg * 4 + 0][d], s0);
            s1 = fmaf(qv, Ks[kg * 4 + 1][d], s1);
            s2 = fmaf(qv, Ks[kg * 4 + 2][d], s2);
            s3 = fmaf(qv, Ks[kg * 4 + 3][d], s3);
        }
        const int kb = k0 + kg * 4;
        s0 = (kb + 0 <= qabs) ? s0 * scale : -INFINITY;
        s1 = (kb + 1 <= qabs) ? s1 * scale : -INFINITY;
        s2 = (kb + 2 <= qabs) ? s2 * scale : -INFINITY;
        s3 = (kb + 3 <= qabs) ? s3 * scale : -INFINITY;

        // row reduction across the 8 lanes that share qi (consecutive lanes)
        float mt = fmaxf(fmaxf(s0, s1), fmaxf(s2, s3));
        mt = fmaxf(mt, __shfl_xor(mt, 1));
        mt = fmaxf(mt, __shfl_xor(mt, 2));
        mt = fmaxf(mt, __shfl_xor(mt, 4));
        const float m_new = fmaxf(m_i, mt);   // finite from first tile (kb=0 valid)

        float p0 = __expf(s0 - m_new);
        float p1 = __expf(s1 - m_new);
        float p2 = __expf(s2 - m_new);
        float p3 = __expf(s3 - m_new);
        float lt = p0 + p1 + p2 + p3;
        lt += __shfl_xor(lt, 1);
        lt += __shfl_xor(lt, 2);
        lt += __shfl_xor(lt, 4);

        const float alpha = __expf(m_i - m_new);   // iter 0: exp(-inf)=0, never NaN
        l_i = l_i * alpha + lt;
        m_i = m_new;

        Ps[qi][kg * 4 + 0] = p0;
        Ps[qi][kg * 4 + 1] = p1;
        Ps[qi][kg * 4 + 2] = p2;
        Ps[qi][kg * 4 + 3] = p3;

#pragma unroll
        for (int i = 0; i < 8; i++) o[i] *= alpha;
        __syncthreads();

        // ---- O += P @ V : thread does row qi, cols oc..oc+7
#pragma unroll 4
        for (int kj = 0; kj < TK; kj++) {
            float pv = Ps[qi][kj];
            float4 v0 = *(const float4*)&Vs[kj][oc];
            float4 v1 = *(const float4*)&Vs[kj][oc + 4];
            o[0] = fmaf(pv, v0.x, o[0]);
            o[1] = fmaf(pv, v0.y, o[1]);
            o[2] = fmaf(pv, v0.z, o[2]);
            o[3] = fmaf(pv, v0.w, o[3]);
            o[4] = fmaf(pv, v1.x, o[4]);
            o[5] = fmaf(pv, v1.y, o[5]);
            o[6] = fmaf(pv, v1.z, o[6]);
            o[7] = fmaf(pv, v1.w, o[7]);
        }
    }

    const float inv = 1.f / l_i;   // l_i > 0: diagonal always unmasked
    float* dst = out + ((size_t)(b * S_ + q0 + qi)) * D_ + h * HD + oc;
    float4 r0 = make_float4(o[0] * inv, o[1] * inv, o[2] * inv, o[3] * inv);
    float4 r1 = make_float4(o[4] * inv, o[5] * inv, o[6] * inv, o[7] * inv);
    *(float4*)dst       = r0;
    *(float4*)(dst + 4) = r1;
}

// ---------------------------------------------------------------------------
extern "C" void kernel_launch(void* const* d_in, const int* in_sizes, int n_in,
                              void* d_out, int out_size, void* d_ws, size_t ws_size,
                              hipStream_t stream)
{
    const float* hs     = (const float*)d_in[0];   // [2,2048,1024]
    const float* attn_w = (const float*)d_in[1];   // [1024,3072]
    const float* attn_b = (const float*)d_in[2];   // [3072]
    const float* proj_w = (const float*)d_in[3];   // [1024,1024]
    const float* proj_b = (const float*)d_in[4];   // [1024]
    float* outp = (float*)d_out;                   // [2,2048,1024]

    float* qkv      = (float*)d_ws;                     // M_ x 3072
    float* attn_out = qkv + (size_t)M_ * N_QKV;         // M_ x 1024

    dim3 blk(256);
    // 1) qkv = hs @ c_attn_w + c_attn_b
    sgemm_bias<<<dim3(N_QKV / 128, M_ / 128), blk, 0, stream>>>(
        hs, attn_w, attn_b, qkv, M_, N_QKV, D_);
    // 2) causal attention -> attn_out [B,S,D] (head-merged layout)
    flash_attn<<<dim3(S_ / TQ, B_ * H_), blk, 0, stream>>>(qkv, attn_out);
    // 3) out = attn_out @ c_proj_w + c_proj_b
    sgemm_bias<<<dim3(D_ / 128, M_ / 128), blk, 0, stream>>>(
        attn_out, proj_w, proj_b, outp, M_, D_, D_);
}

// Round 3
// 842.511 us; speedup vs baseline: 1.5555x; 1.5555x over previous
//
#include <hip/hip_runtime.h>
#include <math.h>

#define B_ 2
#define S_ 2048
#define D_ 1024
#define H_ 16
#define HD 64
#define M_ (B_ * S_)     // 4096
#define N_QKV (3 * D_)   // 3072

typedef short short8 __attribute__((ext_vector_type(8)));
typedef float floatx4 __attribute__((ext_vector_type(4)));

static __device__ __forceinline__ unsigned short f2bf_rne(float x) {
    union { float f; unsigned u; } v; v.f = x;
    unsigned r = v.u + 0x7FFFu + ((v.u >> 16) & 1u);
    return (unsigned short)(r >> 16);
}
static __device__ __forceinline__ float bf2f(unsigned short b) {
    union { unsigned u; float f; } v; v.u = ((unsigned)b) << 16;
    return v.f;
}

// ---------------------------------------------------------------------------
// C[M,N] = A[M,K]@B[K,N] + bias  via split-bf16 (hi+lo) 3-MFMA trick.
// 128x128 tile, BK=32, 256 threads (4 waves, each 64x64 via 4x4 mfma blocks).
// A staged as Am[m][k] bf16 hi/lo; B staged transposed Bt[n][k] hi/lo
// (k-pairs packed as u32 to keep the transpose writes 4-byte).
// ---------------------------------------------------------------------------
__global__ __launch_bounds__(256) void gemm_bf16x3(
    const float* __restrict__ A, const float* __restrict__ Bm,
    const float* __restrict__ bias, float* __restrict__ C,
    int M, int N, int K)
{
    __shared__ unsigned short Ahi[128 * 32];
    __shared__ unsigned short Alo[128 * 32];
    __shared__ unsigned short Bhi[128 * 32];   // Bt[n][k]
    __shared__ unsigned short Blo[128 * 32];

    const int t    = threadIdx.x;
    const int m0   = blockIdx.y * 128, n0 = blockIdx.x * 128;
    const int lane = t & 63, wave = t >> 6;
    const int lm   = lane & 15, quad = lane >> 4;
    const int wm   = (wave >> 1) * 64, wn = (wave & 1) * 64;

    const int arow = t >> 1, acg = (t & 1) * 16;     // A staging: row, k-group
    const int kp   = t & 15, nc = t >> 4;            // B staging: k-pair, n-chunk

    const float* Ap = A + (size_t)(m0 + arow) * K + acg;
    const float* Bp = Bm + (size_t)(2 * kp) * N + n0 + nc * 8;

    floatx4 acc[4][4];
#pragma unroll
    for (int i = 0; i < 4; i++)
#pragma unroll
        for (int j = 0; j < 4; j++)
#pragma unroll
            for (int r = 0; r < 4; r++) acc[i][j][r] = 0.f;

    for (int k0 = 0; k0 < K; k0 += 32) {
        __syncthreads();
        // ---- stage A: 16 fp32 -> bf16 hi/lo, packed pairs -> 2x uint4 each
        {
            const float* src = Ap + k0;
            unsigned hi[8], lo[8];
#pragma unroll
            for (int g = 0; g < 4; g++) {
                float4 vv = *(const float4*)(src + g * 4);
                float xs[4] = {vv.x, vv.y, vv.z, vv.w};
                unsigned short h[4], l[4];
#pragma unroll
                for (int e = 0; e < 4; e++) {
                    h[e] = f2bf_rne(xs[e]);
                    l[e] = f2bf_rne(xs[e] - bf2f(h[e]));
                }
                hi[g * 2 + 0] = (unsigned)h[0] | ((unsigned)h[1] << 16);
                hi[g * 2 + 1] = (unsigned)h[2] | ((unsigned)h[3] << 16);
                lo[g * 2 + 0] = (unsigned)l[0] | ((unsigned)l[1] << 16);
                lo[g * 2 + 1] = (unsigned)l[2] | ((unsigned)l[3] << 16);
            }
            unsigned* dh = (unsigned*)&Ahi[arow * 32 + acg];
            unsigned* dl = (unsigned*)&Alo[arow * 32 + acg];
            *(uint4*)(dh + 0) = make_uint4(hi[0], hi[1], hi[2], hi[3]);
            *(uint4*)(dh + 4) = make_uint4(hi[4], hi[5], hi[6], hi[7]);
            *(uint4*)(dl + 0) = make_uint4(lo[0], lo[1], lo[2], lo[3]);
            *(uint4*)(dl + 4) = make_uint4(lo[4], lo[5], lo[6], lo[7]);
        }
        // ---- stage B transposed: rows k0+2kp, k0+2kp+1, cols nc*8..+7
        {
            const float* r0 = Bp + (size_t)k0 * N;
            const float* r1 = r0 + N;
            float4 a0 = *(const float4*)(r0);
            float4 a1 = *(const float4*)(r0 + 4);
            float4 c0 = *(const float4*)(r1);
            float4 c1 = *(const float4*)(r1 + 4);
            float x0[8] = {a0.x, a0.y, a0.z, a0.w, a1.x, a1.y, a1.z, a1.w};
            float x1[8] = {c0.x, c0.y, c0.z, c0.w, c1.x, c1.y, c1.z, c1.w};
#pragma unroll
            for (int u = 0; u < 8; u++) {
                unsigned short h0 = f2bf_rne(x0[u]);
                unsigned short h1 = f2bf_rne(x1[u]);
                unsigned short l0 = f2bf_rne(x0[u] - bf2f(h0));
                unsigned short l1 = f2bf_rne(x1[u] - bf2f(h1));
                ((unsigned*)Bhi)[(nc * 8 + u) * 16 + kp] = (unsigned)h0 | ((unsigned)h1 << 16);
                ((unsigned*)Blo)[(nc * 8 + u) * 16 + kp] = (unsigned)l0 | ((unsigned)l1 << 16);
            }
        }
        __syncthreads();

        short8 bh[4], bl[4];
#pragma unroll
        for (int nb = 0; nb < 4; nb++) {
            const int r = wn + nb * 16 + lm;
            bh[nb] = *(const short8*)&Bhi[r * 32 + quad * 8];
            bl[nb] = *(const short8*)&Blo[r * 32 + quad * 8];
        }
#pragma unroll
        for (int mb = 0; mb < 4; mb++) {
            const int r = wm + mb * 16 + lm;
            short8 ah = *(const short8*)&Ahi[r * 32 + quad * 8];
            short8 al = *(const short8*)&Alo[r * 32 + quad * 8];
#pragma unroll
            for (int nb = 0; nb < 4; nb++) {
                acc[mb][nb] = __builtin_amdgcn_mfma_f32_16x16x32_bf16(ah, bh[nb], acc[mb][nb], 0, 0, 0);
                acc[mb][nb] = __builtin_amdgcn_mfma_f32_16x16x32_bf16(ah, bl[nb], acc[mb][nb], 0, 0, 0);
                acc[mb][nb] = __builtin_amdgcn_mfma_f32_16x16x32_bf16(al, bh[nb], acc[mb][nb], 0, 0, 0);
            }
        }
    }

    // epilogue: C/D layout col=lane&15, row=quad*4+reg
#pragma unroll
    for (int nb = 0; nb < 4; nb++) {
        const int col = n0 + wn + nb * 16 + lm;
        const float bv = bias[col];
#pragma unroll
        for (int mb = 0; mb < 4; mb++) {
            const int rowb = m0 + wm + mb * 16 + quad * 4;
#pragma unroll
            for (int r = 0; r < 4; r++)
                C[(size_t)(rowb + r) * N + col] = acc[mb][nb][r] + bv;
        }
    }
}

// ---------------------------------------------------------------------------
// Causal flash attention, fp32, 64x64 tiles, 4x4 register micro-tiles.
// Qt[d][q], Kt[d][k] transposed in LDS so the S-phase d-loop is pure b128
// reads; Ps (P row-major [q][k], stride 68) aliases Kt. Vs[k][d] stride 68.
// Thread (ty=t>>4, tx=t&15): S-phase owns q=4ty+i, k=4tx+j;
// PV-phase owns q=4ty+i, d=4tx+j. Row softmax state reduced over tx lanes.
// ---------------------------------------------------------------------------
#define TQ 64
#define TK 64

__global__ __launch_bounds__(256) void flash_attn(
    const float* __restrict__ qkv, float* __restrict__ out)
{
    __shared__ float Qt[HD][TQ];            // 16 KB, Q^T pre-scaled by 1/8
    __shared__ float KtPs[TK * (TQ + 4)];   // 17 KB union: Kt[d][k] s64 | Ps[q][k] s68
    __shared__ float Vs[TK][HD + 4];        // 17 KB

    const int t  = threadIdx.x;
    const int q0 = blockIdx.x * TQ;
    const int bh = blockIdx.y;
    const int b  = bh >> 4, h = bh & 15;

    const int srow = t & 63, sdg = (t >> 6) * 16;   // transpose-staging map
    const int vrow = t >> 2, vcol = (t & 3) * 16;   // V staging map
    const int tx = t & 15, ty = t >> 4;

    // stage Q (transposed + pre-scaled)
    {
        const float* src = qkv + ((size_t)(b * S_ + q0 + srow)) * N_QKV + h * HD + sdg;
#pragma unroll
        for (int g = 0; g < 4; g++) {
            float4 v = *(const float4*)(src + g * 4);
            Qt[sdg + g * 4 + 0][srow] = v.x * 0.125f;
            Qt[sdg + g * 4 + 1][srow] = v.y * 0.125f;
            Qt[sdg + g * 4 + 2][srow] = v.z * 0.125f;
            Qt[sdg + g * 4 + 3][srow] = v.w * 0.125f;
        }
    }

    float m_i[4], l_i[4], o[4][4];
#pragma unroll
    for (int i = 0; i < 4; i++) {
        m_i[i] = -INFINITY; l_i[i] = 0.f;
#pragma unroll
        for (int j = 0; j < 4; j++) o[i][j] = 0.f;
    }

    const float* kbase = qkv + (size_t)b * S_ * N_QKV + D_ + h * HD;
    const float* vbase = kbase + D_;
    const int ntiles = blockIdx.x + 1;

    for (int kt = 0; kt < ntiles; kt++) {
        const int k0 = kt * TK;
        __syncthreads();   // prior PV reads of Ps/Vs complete
        {
            const float* src = kbase + (size_t)(k0 + srow) * N_QKV + sdg;
#pragma unroll
            for (int g = 0; g < 4; g++) {
                float4 v = *(const float4*)(src + g * 4);
                KtPs[(sdg + g * 4 + 0) * TK + srow] = v.x;
                KtPs[(sdg + g * 4 + 1) * TK + srow] = v.y;
                KtPs[(sdg + g * 4 + 2) * TK + srow] = v.z;
                KtPs[(sdg + g * 4 + 3) * TK + srow] = v.w;
            }
        }
        {
            const float* src = vbase + (size_t)(k0 + vrow) * N_QKV + vcol;
#pragma unroll
            for (int g = 0; g < 4; g++)
                *(float4*)&Vs[vrow][vcol + g * 4] = *(const float4*)(src + g * 4);
        }
        __syncthreads();

        // ---- S = (Q/8) K^T : 2x b128 -> 16 FMA per d
        float s[4][4];
#pragma unroll
        for (int i = 0; i < 4; i++)
#pragma unroll
            for (int j = 0; j < 4; j++) s[i][j] = 0.f;
#pragma unroll 8
        for (int d = 0; d < HD; d++) {
            float4 a  = *(const float4*)&Qt[d][ty * 4];
            float4 bk = *(const float4*)&KtPs[d * TK + tx * 4];
            float av[4] = {a.x, a.y, a.z, a.w};
            float bv[4] = {bk.x, bk.y, bk.z, bk.w};
#pragma unroll
            for (int i = 0; i < 4; i++)
#pragma unroll
                for (int j = 0; j < 4; j++)
                    s[i][j] = fmaf(av[i], bv[j], s[i][j]);
        }
        if (k0 == q0) {   // diagonal tile: causal mask (wave-uniform branch)
#pragma unroll
            for (int i = 0; i < 4; i++)
#pragma unroll
                for (int j = 0; j < 4; j++)
                    if (k0 + tx * 4 + j > q0 + ty * 4 + i) s[i][j] = -INFINITY;
        }

        // ---- online softmax per row (reduce across the 16 tx lanes)
        float alpha[4];
#pragma unroll
        for (int i = 0; i < 4; i++) {
            float mt = fmaxf(fmaxf(s[i][0], s[i][1]), fmaxf(s[i][2], s[i][3]));
            mt = fmaxf(mt, __shfl_xor(mt, 1));
            mt = fmaxf(mt, __shfl_xor(mt, 2));
            mt = fmaxf(mt, __shfl_xor(mt, 4));
            mt = fmaxf(mt, __shfl_xor(mt, 8));
            const float mn = fmaxf(m_i[i], mt);
            alpha[i] = __expf(m_i[i] - mn);
            m_i[i] = mn;
            float lt = 0.f;
#pragma unroll
            for (int j = 0; j < 4; j++) { s[i][j] = __expf(s[i][j] - mn); lt += s[i][j]; }
            lt += __shfl_xor(lt, 1);
            lt += __shfl_xor(lt, 2);
            lt += __shfl_xor(lt, 4);
            lt += __shfl_xor(lt, 8);
            l_i[i] = l_i[i] * alpha[i] + lt;
        }
        __syncthreads();   // all lanes done reading Kt (about to overwrite with Ps)
#pragma unroll
        for (int i = 0; i < 4; i++) {
            *(float4*)&KtPs[(ty * 4 + i) * (TK + 4) + tx * 4] =
                make_float4(s[i][0], s[i][1], s[i][2], s[i][3]);
#pragma unroll
            for (int j = 0; j < 4; j++) o[i][j] *= alpha[i];
        }
        __syncthreads();   // Ps visible

        // ---- O += P @ V : 8x b128 -> 64 FMA per 4-k group
#pragma unroll 4
        for (int kg = 0; kg < TK / 4; kg++) {
            float4 p[4], vv[4];
#pragma unroll
            for (int i = 0; i < 4; i++)
                p[i] = *(const float4*)&KtPs[(ty * 4 + i) * (TK + 4) + kg * 4];
#pragma unroll
            for (int j = 0; j < 4; j++)
                vv[j] = *(const float4*)&Vs[kg * 4 + j][tx * 4];
#pragma unroll
            for (int i = 0; i < 4; i++) {
                float pj[4] = {p[i].x, p[i].y, p[i].z, p[i].w};
#pragma unroll
                for (int j = 0; j < 4; j++) {
                    o[i][0] = fmaf(pj[j], vv[j].x, o[i][0]);
                    o[i][1] = fmaf(pj[j], vv[j].y, o[i][1]);
                    o[i][2] = fmaf(pj[j], vv[j].z, o[i][2]);
                    o[i][3] = fmaf(pj[j], vv[j].w, o[i][3]);
                }
            }
        }
    }

#pragma unroll
    for (int i = 0; i < 4; i++) {
        const float inv = 1.f / l_i[i];
        float* dst = out + ((size_t)(b * S_ + q0 + ty * 4 + i)) * D_ + h * HD + tx * 4;
        *(float4*)dst = make_float4(o[i][0] * inv, o[i][1] * inv, o[i][2] * inv, o[i][3] * inv);
    }
}

// ---------------------------------------------------------------------------
extern "C" void kernel_launch(void* const* d_in, const int* in_sizes, int n_in,
                              void* d_out, int out_size, void* d_ws, size_t ws_size,
                              hipStream_t stream)
{
    const float* hs     = (const float*)d_in[0];
    const float* attn_w = (const float*)d_in[1];
    const float* attn_b = (const float*)d_in[2];
    const float* proj_w = (const float*)d_in[3];
    const float* proj_b = (const float*)d_in[4];
    float* outp = (float*)d_out;

    float* qkv      = (float*)d_ws;                 // M_ x 3072
    float* attn_out = qkv + (size_t)M_ * N_QKV;     // M_ x 1024

    dim3 blk(256);
    gemm_bf16x3<<<dim3(N_QKV / 128, M_ / 128), blk, 0, stream>>>(
        hs, attn_w, attn_b, qkv, M_, N_QKV, D_);
    flash_attn<<<dim3(S_ / TQ, B_ * H_), blk, 0, stream>>>(qkv, attn_out);
    gemm_bf16x3<<<dim3(D_ / 128, M_ / 128), blk, 0, stream>>>(
        attn_out, proj_w, proj_b, outp, M_, D_, D_);
}

// Round 4
// 422.770 us; speedup vs baseline: 3.0998x; 1.9928x over previous
//
#include <hip/hip_runtime.h>
#include <math.h>

#define B_ 2
#define S_ 2048
#define D_ 1024
#define H_ 16
#define HD 64
#define M_ (B_ * S_)     // 4096
#define N_QKV (3 * D_)   // 3072

typedef short short8 __attribute__((ext_vector_type(8)));
typedef float floatx4 __attribute__((ext_vector_type(4)));

static __device__ __forceinline__ unsigned short f2bf_rne(float x) {
    union { float f; unsigned u; } v; v.f = x;
    unsigned r = v.u + 0x7FFFu + ((v.u >> 16) & 1u);
    return (unsigned short)(r >> 16);
}
static __device__ __forceinline__ float bf2f(unsigned short b) {
    union { unsigned u; float f; } v; v.u = ((unsigned)b) << 16;
    return v.f;
}
static __device__ __forceinline__ void split2(float x, unsigned short& h, unsigned short& l) {
    h = f2bf_rne(x);
    l = f2bf_rne(x - bf2f(h));
}

// ---------------------------------------------------------------------------
// GEMM: unchanged from R3 (verified working, absmax 1.95e-3).
// ---------------------------------------------------------------------------
__global__ __launch_bounds__(256) void gemm_bf16x3(
    const float* __restrict__ A, const float* __restrict__ Bm,
    const float* __restrict__ bias, float* __restrict__ C,
    int M, int N, int K)
{
    __shared__ unsigned short Ahi[128 * 32];
    __shared__ unsigned short Alo[128 * 32];
    __shared__ unsigned short Bhi[128 * 32];
    __shared__ unsigned short Blo[128 * 32];

    const int t    = threadIdx.x;
    const int m0   = blockIdx.y * 128, n0 = blockIdx.x * 128;
    const int lane = t & 63, wave = t >> 6;
    const int lm   = lane & 15, quad = lane >> 4;
    const int wm   = (wave >> 1) * 64, wn = (wave & 1) * 64;

    const int arow = t >> 1, acg = (t & 1) * 16;
    const int kp   = t & 15, nc = t >> 4;

    const float* Ap = A + (size_t)(m0 + arow) * K + acg;
    const float* Bp = Bm + (size_t)(2 * kp) * N + n0 + nc * 8;

    floatx4 acc[4][4];
#pragma unroll
    for (int i = 0; i < 4; i++)
#pragma unroll
        for (int j = 0; j < 4; j++)
#pragma unroll
            for (int r = 0; r < 4; r++) acc[i][j][r] = 0.f;

    for (int k0 = 0; k0 < K; k0 += 32) {
        __syncthreads();
        {
            const float* src = Ap + k0;
            unsigned hi[8], lo[8];
#pragma unroll
            for (int g = 0; g < 4; g++) {
                float4 vv = *(const float4*)(src + g * 4);
                float xs[4] = {vv.x, vv.y, vv.z, vv.w};
                unsigned short h[4], l[4];
#pragma unroll
                for (int e = 0; e < 4; e++) split2(xs[e], h[e], l[e]);
                hi[g * 2 + 0] = (unsigned)h[0] | ((unsigned)h[1] << 16);
                hi[g * 2 + 1] = (unsigned)h[2] | ((unsigned)h[3] << 16);
                lo[g * 2 + 0] = (unsigned)l[0] | ((unsigned)l[1] << 16);
                lo[g * 2 + 1] = (unsigned)l[2] | ((unsigned)l[3] << 16);
            }
            unsigned* dh = (unsigned*)&Ahi[arow * 32 + acg];
            unsigned* dl = (unsigned*)&Alo[arow * 32 + acg];
            *(uint4*)(dh + 0) = make_uint4(hi[0], hi[1], hi[2], hi[3]);
            *(uint4*)(dh + 4) = make_uint4(hi[4], hi[5], hi[6], hi[7]);
            *(uint4*)(dl + 0) = make_uint4(lo[0], lo[1], lo[2], lo[3]);
            *(uint4*)(dl + 4) = make_uint4(lo[4], lo[5], lo[6], lo[7]);
        }
        {
            const float* r0 = Bp + (size_t)k0 * N;
            const float* r1 = r0 + N;
            float4 a0 = *(const float4*)(r0);
            float4 a1 = *(const float4*)(r0 + 4);
            float4 c0 = *(const float4*)(r1);
            float4 c1 = *(const float4*)(r1 + 4);
            float x0[8] = {a0.x, a0.y, a0.z, a0.w, a1.x, a1.y, a1.z, a1.w};
            float x1[8] = {c0.x, c0.y, c0.z, c0.w, c1.x, c1.y, c1.z, c1.w};
#pragma unroll
            for (int u = 0; u < 8; u++) {
                unsigned short h0, l0, h1, l1;
                split2(x0[u], h0, l0);
                split2(x1[u], h1, l1);
                ((unsigned*)Bhi)[(nc * 8 + u) * 16 + kp] = (unsigned)h0 | ((unsigned)h1 << 16);
                ((unsigned*)Blo)[(nc * 8 + u) * 16 + kp] = (unsigned)l0 | ((unsigned)l1 << 16);
            }
        }
        __syncthreads();

        short8 bh[4], bl[4];
#pragma unroll
        for (int nb = 0; nb < 4; nb++) {
            const int r = wn + nb * 16 + lm;
            bh[nb] = *(const short8*)&Bhi[r * 32 + quad * 8];
            bl[nb] = *(const short8*)&Blo[r * 32 + quad * 8];
        }
#pragma unroll
        for (int mb = 0; mb < 4; mb++) {
            const int r = wm + mb * 16 + lm;
            short8 ah = *(const short8*)&Ahi[r * 32 + quad * 8];
            short8 al = *(const short8*)&Alo[r * 32 + quad * 8];
#pragma unroll
            for (int nb = 0; nb < 4; nb++) {
                acc[mb][nb] = __builtin_amdgcn_mfma_f32_16x16x32_bf16(ah, bh[nb], acc[mb][nb], 0, 0, 0);
                acc[mb][nb] = __builtin_amdgcn_mfma_f32_16x16x32_bf16(ah, bl[nb], acc[mb][nb], 0, 0, 0);
                acc[mb][nb] = __builtin_amdgcn_mfma_f32_16x16x32_bf16(al, bh[nb], acc[mb][nb], 0, 0, 0);
            }
        }
    }

#pragma unroll
    for (int nb = 0; nb < 4; nb++) {
        const int col = n0 + wn + nb * 16 + lm;
        const float bv = bias[col];
#pragma unroll
        for (int mb = 0; mb < 4; mb++) {
            const int rowb = m0 + wm + mb * 16 + quad * 4;
#pragma unroll
            for (int r = 0; r < 4; r++)
                C[(size_t)(rowb + r) * N + col] = acc[mb][nb][r] + bv;
        }
    }
}

// ---------------------------------------------------------------------------
// MFMA causal flash attention, split-bf16 (3-MFMA) for QK^T and PV.
// 64x64 tiles, 4 waves; wave w owns q-strip [16w,16w+16).
// Q fragments in registers (A-layout, loaded direct from global, pre-scaled).
// K staged [k][d] as u32-packed bf16 d-pairs, row stride 36 u32.
// V staged transposed [d][k] as u32-packed bf16 k-pairs.
// P (post-softmax) aliases the K buffer, A-layout rows q, written b16.
// Work pairing: block j processes q-tiles j and 31-j (uniform 33 k-iters).
// ---------------------------------------------------------------------------
#define PADU 36   // u32 per row: 32 data + 4 pad (2-way max conflicts)

__global__ __launch_bounds__(256) void flash_attn_mfma(
    const float* __restrict__ qkv, float* __restrict__ out)
{
    __shared__ unsigned KPhi[64 * PADU];   // K hi, later P hi
    __shared__ unsigned KPlo[64 * PADU];   // K lo, later P lo
    __shared__ unsigned Vthi[64 * PADU];   // V^T hi
    __shared__ unsigned Vtlo[64 * PADU];   // V^T lo

    const int t    = threadIdx.x;
    const int pj   = blockIdx.x;            // 0..15 (tile pair)
    const int bh   = blockIdx.y;
    const int b    = bh >> 4, h = bh & 15;
    const int lane = t & 63, w = t >> 6;
    const int lm   = lane & 15, quad = lane >> 4;

    const int kr = t >> 2, kc = (t & 3) * 16;   // K staging: row, d-base
    const int vp = t & 31, vd = (t >> 5) * 8;   // V staging: k-pair, d-base

    const float* qkv_b = qkv + (size_t)b * S_ * N_QKV;
    const float* kbase = qkv_b + D_ + h * HD;
    const float* vbase = qkv_b + 2 * D_ + h * HD;

    for (int phse = 0; phse < 2; phse++) {
        const int qt = phse ? (31 - pj) : pj;
        const int q0 = qt * 64;
        const int ntiles = qt + 1;

        // ---- Q fragments (regs): A[m=lm][d = s*32 + quad*8 + j], scaled 1/8
        short8 qh[2], ql[2];
        {
            const float* qsrc = qkv_b + (size_t)(q0 + w * 16 + lm) * N_QKV + h * HD + quad * 8;
#pragma unroll
            for (int s = 0; s < 2; s++) {
                float4 a = *(const float4*)(qsrc + s * 32);
                float4 c = *(const float4*)(qsrc + s * 32 + 4);
                float x[8] = {a.x, a.y, a.z, a.w, c.x, c.y, c.z, c.w};
#pragma unroll
                for (int j = 0; j < 8; j++) {
                    unsigned short hh, ll;
                    split2(x[j] * 0.125f, hh, ll);
                    qh[s][j] = (short)hh;
                    ql[s][j] = (short)ll;
                }
            }
        }

        float m_i[4], l_i[4];
        floatx4 o[4];
#pragma unroll
        for (int r = 0; r < 4; r++) { m_i[r] = -INFINITY; l_i[r] = 0.f; }
#pragma unroll
        for (int nb = 0; nb < 4; nb++)
#pragma unroll
            for (int r = 0; r < 4; r++) o[nb][r] = 0.f;

        for (int kt = 0; kt < ntiles; kt++) {
            const int k0 = kt * 64;
            __syncthreads();   // (1) prior PV reads of KP/Vt complete

            // ---- stage K [k][d]: thread covers row kr, d = kc..kc+15
            {
                const float* src = kbase + (size_t)(k0 + kr) * N_QKV + kc;
                unsigned* dh = &KPhi[kr * PADU + kc / 2];
                unsigned* dl = &KPlo[kr * PADU + kc / 2];
#pragma unroll
                for (int g = 0; g < 4; g++) {
                    float4 v = *(const float4*)(src + g * 4);
                    float xs[4] = {v.x, v.y, v.z, v.w};
                    unsigned short hh[4], ll[4];
#pragma unroll
                    for (int e = 0; e < 4; e++) split2(xs[e], hh[e], ll[e]);
                    uint2 hv = make_uint2((unsigned)hh[0] | ((unsigned)hh[1] << 16),
                                          (unsigned)hh[2] | ((unsigned)hh[3] << 16));
                    uint2 lv = make_uint2((unsigned)ll[0] | ((unsigned)ll[1] << 16),
                                          (unsigned)ll[2] | ((unsigned)ll[3] << 16));
                    *(uint2*)(dh + g * 2) = hv;
                    *(uint2*)(dl + g * 2) = lv;
                }
            }
            // ---- stage V^T [d][k]: thread covers k-pair vp, d = vd..vd+7
            {
                const float* s0 = vbase + (size_t)(k0 + 2 * vp) * N_QKV + vd;
                const float* s1 = s0 + N_QKV;
                float4 a0 = *(const float4*)(s0);
                float4 a1 = *(const float4*)(s0 + 4);
                float4 c0 = *(const float4*)(s1);
                float4 c1 = *(const float4*)(s1 + 4);
                float x0[8] = {a0.x, a0.y, a0.z, a0.w, a1.x, a1.y, a1.z, a1.w};
                float x1[8] = {c0.x, c0.y, c0.z, c0.w, c1.x, c1.y, c1.z, c1.w};
#pragma unroll
                for (int e = 0; e < 8; e++) {
                    unsigned short h0, l0, h1, l1;
                    split2(x0[e], h0, l0);
                    split2(x1[e], h1, l1);
                    Vthi[(vd + e) * PADU + vp] = (unsigned)h0 | ((unsigned)h1 << 16);
                    Vtlo[(vd + e) * PADU + vp] = (unsigned)l0 | ((unsigned)l1 << 16);
                }
            }
            __syncthreads();   // (2) K/V staged

            // ---- S = (Q/8)K^T : acc_s[nb] covers k-cols 16nb..16nb+15
            floatx4 sa[4];
#pragma unroll
            for (int nb = 0; nb < 4; nb++)
#pragma unroll
                for (int r = 0; r < 4; r++) sa[nb][r] = 0.f;
#pragma unroll
            for (int s = 0; s < 2; s++) {
#pragma unroll
                for (int nb = 0; nb < 4; nb++) {
                    short8 kh = *(const short8*)&KPhi[(nb * 16 + lm) * PADU + s * 16 + quad * 4];
                    short8 kl = *(const short8*)&KPlo[(nb * 16 + lm) * PADU + s * 16 + quad * 4];
                    sa[nb] = __builtin_amdgcn_mfma_f32_16x16x32_bf16(qh[s], kh, sa[nb], 0, 0, 0);
                    sa[nb] = __builtin_amdgcn_mfma_f32_16x16x32_bf16(ql[s], kh, sa[nb], 0, 0, 0);
                    sa[nb] = __builtin_amdgcn_mfma_f32_16x16x32_bf16(qh[s], kl, sa[nb], 0, 0, 0);
                }
            }

            // ---- online softmax: lane holds rows q_local = 16w+4quad+r
            const bool diag = (k0 == q0);
            float alpha[4], pv[4][4];
#pragma unroll
            for (int r = 0; r < 4; r++) {
                const int qrow = 16 * w + 4 * quad + r;
                float sv[4];
#pragma unroll
                for (int nb = 0; nb < 4; nb++) {
                    sv[nb] = sa[nb][r];
                    if (diag && (16 * nb + lm > qrow)) sv[nb] = -INFINITY;
                }
                float mt = fmaxf(fmaxf(sv[0], sv[1]), fmaxf(sv[2], sv[3]));
                mt = fmaxf(mt, __shfl_xor(mt, 1));
                mt = fmaxf(mt, __shfl_xor(mt, 2));
                mt = fmaxf(mt, __shfl_xor(mt, 4));
                mt = fmaxf(mt, __shfl_xor(mt, 8));
                const float mn = fmaxf(m_i[r], mt);
                alpha[r] = __expf(m_i[r] - mn);
                m_i[r] = mn;
                float lt = 0.f;
#pragma unroll
                for (int nb = 0; nb < 4; nb++) { pv[r][nb] = __expf(sv[nb] - mn); lt += pv[r][nb]; }
                lt += __shfl_xor(lt, 1);
                lt += __shfl_xor(lt, 2);
                lt += __shfl_xor(lt, 4);
                lt += __shfl_xor(lt, 8);
                l_i[r] = l_i[r] * alpha[r] + lt;
            }
            __syncthreads();   // (3) all waves done reading K fragments

            // ---- write P (A-layout rows q_local, stride 72 shorts) into KP
            {
                unsigned short* Ph = (unsigned short*)KPhi;
                unsigned short* Pl = (unsigned short*)KPlo;
#pragma unroll
                for (int r = 0; r < 4; r++) {
                    const int row = 16 * w + 4 * quad + r;
#pragma unroll
                    for (int nb = 0; nb < 4; nb++) {
                        unsigned short hh, ll;
                        split2(pv[r][nb], hh, ll);
                        Ph[row * (2 * PADU) + 16 * nb + lm] = hh;
                        Pl[row * (2 * PADU) + 16 * nb + lm] = ll;
                    }
                }
#pragma unroll
                for (int nb = 0; nb < 4; nb++)
#pragma unroll
                    for (int r = 0; r < 4; r++) o[nb][r] *= alpha[r];
            }
            __syncthreads();   // (4) P visible

            // ---- O += P V : o[nb2] covers d-cols 16nb2..16nb2+15
#pragma unroll
            for (int ks = 0; ks < 2; ks++) {
                short8 phf = *(const short8*)&KPhi[(16 * w + lm) * PADU + ks * 16 + quad * 4];
                short8 plf = *(const short8*)&KPlo[(16 * w + lm) * PADU + ks * 16 + quad * 4];
#pragma unroll
                for (int nb = 0; nb < 4; nb++) {
                    short8 vh = *(const short8*)&Vthi[(16 * nb + lm) * PADU + ks * 16 + quad * 4];
                    short8 vl = *(const short8*)&Vtlo[(16 * nb + lm) * PADU + ks * 16 + quad * 4];
                    o[nb] = __builtin_amdgcn_mfma_f32_16x16x32_bf16(phf, vh, o[nb], 0, 0, 0);
                    o[nb] = __builtin_amdgcn_mfma_f32_16x16x32_bf16(plf, vh, o[nb], 0, 0, 0);
                    o[nb] = __builtin_amdgcn_mfma_f32_16x16x32_bf16(phf, vl, o[nb], 0, 0, 0);
                }
            }
        }

        // ---- epilogue: normalize and store (C-layout rows 16w+4quad+r)
#pragma unroll
        for (int r = 0; r < 4; r++) {
            const float inv = 1.f / l_i[r];
            float* dst = out + (size_t)(b * S_ + q0 + 16 * w + 4 * quad + r) * D_ + h * HD + lm;
#pragma unroll
            for (int nb = 0; nb < 4; nb++)
                dst[16 * nb] = o[nb][r] * inv;
        }
    }
}

// ---------------------------------------------------------------------------
extern "C" void kernel_launch(void* const* d_in, const int* in_sizes, int n_in,
                              void* d_out, int out_size, void* d_ws, size_t ws_size,
                              hipStream_t stream)
{
    const float* hs     = (const float*)d_in[0];
    const float* attn_w = (const float*)d_in[1];
    const float* attn_b = (const float*)d_in[2];
    const float* proj_w = (const float*)d_in[3];
    const float* proj_b = (const float*)d_in[4];
    float* outp = (float*)d_out;

    float* qkv      = (float*)d_ws;                 // M_ x 3072
    float* attn_out = qkv + (size_t)M_ * N_QKV;     // M_ x 1024

    dim3 blk(256);
    gemm_bf16x3<<<dim3(N_QKV / 128, M_ / 128), blk, 0, stream>>>(
        hs, attn_w, attn_b, qkv, M_, N_QKV, D_);
    flash_attn_mfma<<<dim3(16, B_ * H_), blk, 0, stream>>>(qkv, attn_out);
    gemm_bf16x3<<<dim3(D_ / 128, M_ / 128), blk, 0, stream>>>(
        attn_out, proj_w, proj_b, outp, M_, D_, D_);
}